// Round 7
// baseline (332.715 us; speedup 1.0000x reference)
//
#include <hip/hip_runtime.h>
#include <hip/hip_bf16.h>

namespace {

constexpr int T = 200;

typedef float f32x4 __attribute__((ext_vector_type(4)));
typedef short bf16x8 __attribute__((ext_vector_type(8)));

__device__ __forceinline__ short f2bf(float f) {
  __hip_bfloat16 h = __float2bfloat16(f);  // RNE; pairs fuse to v_cvt_pk_bf16_f32
  return __builtin_bit_cast(short, h);
}
__device__ __forceinline__ float bf2f(short s) {
  return __uint_as_float(((unsigned)(unsigned short)s) << 16);
}

template <int CTRL>
__device__ __forceinline__ float dpp_add(float x) {
  int y = __builtin_amdgcn_update_dpp(0, __float_as_int(x), CTRL, 0xF, 0xF, true);
  return x + __int_as_float(y);
}
__device__ __forceinline__ float sum16(float x) {
  x = dpp_add<0x121>(x); x = dpp_add<0x122>(x);   // row_ror 1,2,4,8
  x = dpp_add<0x124>(x); x = dpp_add<0x128>(x);
  return x;
}

__device__ __forceinline__ void async_cp16(const void* g, void* l) {
  __builtin_amdgcn_global_load_lds((__attribute__((address_space(1))) void*)g,
                                   (__attribute__((address_space(3))) void*)l, 16, 0, 0);
}

// W fragment slot (slot<4096): dt=slot>>9, ks=(slot>>6)&7, lane=slot&63.
// ks<4: (Bm-C)[d][f], f=ks*32+lr*8+j ; ks>=4: Dm[d][f], f=(ks-4)*32+lr*8+j; d=dt*16+(lane&15).
__device__ __forceinline__ bf16x8 w_frag(const float* __restrict__ w1, int slot) {
  int lane = slot & 63, ks = (slot >> 6) & 7, dt = slot >> 9;
  int d = dt * 16 + (lane & 15), lr = lane >> 4;
  const float* r = w1 + (size_t)d * 512;
  bf16x8 v;
  if (ks < 4) {
    int f0 = ks * 32 + lr * 8;
    f32x4 b0 = *(const f32x4*)(r + 128 + f0), b1 = *(const f32x4*)(r + 132 + f0);
    f32x4 c0 = *(const f32x4*)(r + 256 + f0), c1 = *(const f32x4*)(r + 260 + f0);
    v[0]=f2bf(b0.x-c0.x); v[1]=f2bf(b0.y-c0.y); v[2]=f2bf(b0.z-c0.z); v[3]=f2bf(b0.w-c0.w);
    v[4]=f2bf(b1.x-c1.x); v[5]=f2bf(b1.y-c1.y); v[6]=f2bf(b1.z-c1.z); v[7]=f2bf(b1.w-c1.w);
  } else {
    int f0 = (ks - 4) * 32 + lr * 8;
    f32x4 d0 = *(const f32x4*)(r + 384 + f0), d1 = *(const f32x4*)(r + 388 + f0);
    v[0]=f2bf(d0.x); v[1]=f2bf(d0.y); v[2]=f2bf(d0.z); v[3]=f2bf(d0.w);
    v[4]=f2bf(d1.x); v[5]=f2bf(d1.y); v[6]=f2bf(d1.z); v[7]=f2bf(d1.w);
  }
  return v;
}

__global__ void preW_kernel(const float* __restrict__ w1, unsigned short* __restrict__ Wp,
                            float* __restrict__ sTd) {
  int idx = blockIdx.x * 256 + threadIdx.x;  // 64*256 = 16384
  int d = idx >> 7, f = idx & 127;
  sTd[idx] = w1[(size_t)d * 512 + f] + w1[(size_t)d * 512 + 256 + f];  // (A+C), d-major
  if (idx < 4096) *(bf16x8*)(Wp + (size_t)idx * 8) = w_frag(w1, idx);
}

__device__ __forceinline__ bool mask_at(const void* m, int mcode, size_t i) {
  if (mcode == 0) return ((const int*)m)[i] != 0;
  if (mcode == 1) return ((const unsigned char*)m)[i] != 0;
  return ((const float*)m)[i] != 0.f;
}

__global__ __launch_bounds__(256, 2) void din_kernel(
    const float* __restrict__ qg, const float* __restrict__ keysg,
    const void* __restrict__ maskg, const float* __restrict__ w1g,
    const float* __restrict__ b1g, const float* __restrict__ pag,
    const float* __restrict__ w2g, const float* __restrict__ b2g,
    const unsigned short* __restrict__ Wp, const float* __restrict__ sTd,
    int mode, float* __restrict__ outg) {
  __shared__ __align__(16) unsigned short Wlds[32768];  // 64 KB frag table

  const int tid  = threadIdx.x;
  const int wid  = tid >> 6;               // 0..3
  const int lane = tid & 63;
  const int lrow = lane >> 4;              // 0..3
  const int lcol = lane & 15;
  const int b    = (blockIdx.x << 2) + wid;  // wave owns batch b outright

  const float* qb    = qg + (size_t)b * 128;
  const float* keysB = keysg + (size_t)b * T * 128;

  // ---- mask dtype detector (wave-uniform) ----
  int mcode;
  {
    unsigned v = ((const unsigned*)maskg)[lane];
    unsigned c0 = v & 255u, c1 = (v >> 8) & 255u, c2 = (v >> 16) & 255u, c3 = v >> 24;
    bool weird = (c0 == 0x80u) | (c0 == 0x3Fu) | (c1 == 0x80u) | (c1 == 0x3Fu) |
                 (c2 == 0x80u) | (c2 == 0x3Fu) | (c3 == 0x80u) | (c3 == 0x3Fu);
    bool nz = (v & 0xFFFFFF00u) != 0u;
    unsigned long long bw = __ballot(weird);
    unsigned long long bn = __ballot(nz);
    mcode = bw ? 2 : (bn ? 1 : 0);  // 2=f32, 1=byte, 0=int32
  }

  const float pa  = pag[0];
  const float b2v = b2g[0];

  // ---- K tile 0 prefetch into kf (A-frag: row=lcol, f=ks*32+lrow*8+j) ----
  f32x4 kf0[4], kf1[4];
  #define LOADK2(TILE, KS0, KS1)                                   \
    do {                                                           \
      int trow_ = (TILE) * 16 + lcol;                              \
      int trc_ = trow_ < T ? trow_ : T - 1;                        \
      const float* kr_ = keysB + (size_t)trc_ * 128 + lrow * 8;    \
      kf0[KS0] = *(const f32x4*)(kr_ + (KS0) * 32);                \
      kf1[KS0] = *(const f32x4*)(kr_ + (KS0) * 32 + 4);            \
      kf0[KS1] = *(const f32x4*)(kr_ + (KS1) * 32);                \
      kf1[KS1] = *(const f32x4*)(kr_ + (KS1) * 32 + 4);            \
    } while (0)
  LOADK2(0, 0, 1);
  LOADK2(0, 2, 3);

  // ---- stage W: 64 KB, linear, conflict-free ----
  if (mode) {
    #pragma unroll
    for (int i = 0; i < 16; ++i)
      async_cp16((const char*)Wp + ((size_t)tid + i * 256) * 16,
                 (char*)Wlds + ((size_t)tid + i * 256) * 16);
  } else {
    #pragma unroll
    for (int i = 0; i < 16; ++i) {
      int slot = tid + i * 256;
      *(bf16x8*)((char*)Wlds + (size_t)slot * 16) = w_frag(w1g, slot);
    }
  }

  // ---- u_d[8]: u[d]=b1[d]+sum_f q[f](A+C)[d][f]; lrow-split f-quarters + shfl ----
  float u_d[8];
  {
    f32x4 qq[8];
    #pragma unroll
    for (int i = 0; i < 8; ++i) qq[i] = *(const f32x4*)(qb + lrow * 32 + i * 4);
    #pragma unroll
    for (int dt = 0; dt < 8; ++dt) {
      int d = dt * 16 + lcol;
      float acc = 0.f;
      if (mode) {
        const float* sp = sTd + (size_t)d * 128 + lrow * 32;
        #pragma unroll
        for (int i = 0; i < 8; ++i) {
          f32x4 sv = *(const f32x4*)(sp + i * 4);
          acc += qq[i].x*sv.x + qq[i].y*sv.y + qq[i].z*sv.z + qq[i].w*sv.w;
        }
      } else {
        const float* r = w1g + (size_t)d * 512 + lrow * 32;
        #pragma unroll
        for (int i = 0; i < 8; ++i) {
          f32x4 av = *(const f32x4*)(r + i * 4);
          f32x4 cv = *(const f32x4*)(r + 256 + i * 4);
          acc += qq[i].x*(av.x+cv.x) + qq[i].y*(av.y+cv.y) +
                 qq[i].z*(av.z+cv.z) + qq[i].w*(av.w+cv.w);
        }
      }
      acc += __shfl_xor(acc, 16);
      acc += __shfl_xor(acc, 32);
      u_d[dt] = acc + b1g[d];
    }
  }

  // ---- mask -> 4 wave-uniform u64 bitmasks (bit l of mw_k = valid(t=k*64+l)) ----
  unsigned long long mw0, mw1, mw2, mw3;
  {
    size_t base = (size_t)b * T;
    bool v0 = mask_at(maskg, mcode, base + lane);
    bool v1 = mask_at(maskg, mcode, base + 64 + lane);
    bool v2 = mask_at(maskg, mcode, base + 128 + lane);
    bool v3 = (192 + lane < T) ? mask_at(maskg, mcode, base + 192 + lane) : false;
    mw0 = __ballot(v0); mw1 = __ballot(v1); mw2 = __ballot(v2); mw3 = __ballot(v3);
  }

  // ---- q fragments (f-slots match kf) and w2 ----
  f32x4 qf0[4], qf1[4];
  #pragma unroll
  for (int ks = 0; ks < 4; ++ks) {
    qf0[ks] = *(const f32x4*)(qb + ks * 32 + lrow * 8);
    qf1[ks] = *(const f32x4*)(qb + ks * 32 + lrow * 8 + 4);
  }
  float w2d[8];
  #pragma unroll
  for (int dt = 0; dt < 8; ++dt) w2d[dt] = w2g[dt * 16 + lcol];

  __syncthreads();  // THE barrier: W staged; waves free-run after this

  float m_w = -1e9f, den_w = 0.f;
  float accpv[32];
  #pragma unroll
  for (int i = 0; i < 32; ++i) accpv[i] = 0.f;

  #define MFMA_DT(DT)                                                           \
    {                                                                           \
      f32x4 acc = {u_d[DT], u_d[DT], u_d[DT], u_d[DT]};                         \
      _Pragma("unroll")                                                         \
      for (int ks = 0; ks < 4; ++ks)                                            \
        acc = __builtin_amdgcn_mfma_f32_16x16x32_bf16(af[ks],                   \
              *(const bf16x8*)((const char*)Wlds + (((DT)*8+ks)*64+lane)*16),   \
              acc, 0, 0, 0);                                                    \
      _Pragma("unroll")                                                         \
      for (int ks = 0; ks < 4; ++ks)                                            \
        acc = __builtin_amdgcn_mfma_f32_16x16x32_bf16(afq[ks],                  \
              *(const bf16x8*)((const char*)Wlds + (((DT)*8+4+ks)*64+lane)*16), \
              acc, 0, 0, 0);                                                    \
      _Pragma("unroll")                                                         \
      for (int j = 0; j < 4; ++j) {                                             \
        float h = acc[j];                                                       \
        h = (h >= 0.f) ? h : pa * h;                                            \
        sj[j] += h * w2d[DT];                                                   \
      }                                                                         \
    }

  for (int tile = 0; tile < 13; ++tile) {
    // convert kf -> af (k) + afq (q*k), freeing fp32 kf for the next prefetch
    bf16x8 af[4], afq[4];
    #pragma unroll
    for (int ks = 0; ks < 4; ++ks) {
      af[ks][0]=f2bf(kf0[ks].x); af[ks][1]=f2bf(kf0[ks].y);
      af[ks][2]=f2bf(kf0[ks].z); af[ks][3]=f2bf(kf0[ks].w);
      af[ks][4]=f2bf(kf1[ks].x); af[ks][5]=f2bf(kf1[ks].y);
      af[ks][6]=f2bf(kf1[ks].z); af[ks][7]=f2bf(kf1[ks].w);
      afq[ks][0]=f2bf(kf0[ks].x*qf0[ks].x); afq[ks][1]=f2bf(kf0[ks].y*qf0[ks].y);
      afq[ks][2]=f2bf(kf0[ks].z*qf0[ks].z); afq[ks][3]=f2bf(kf0[ks].w*qf0[ks].w);
      afq[ks][4]=f2bf(kf1[ks].x*qf1[ks].x); afq[ks][5]=f2bf(kf1[ks].y*qf1[ks].y);
      afq[ks][6]=f2bf(kf1[ks].z*qf1[ks].z); afq[ks][7]=f2bf(kf1[ks].w*qf1[ks].w);
    }
    if (tile < 12) LOADK2(tile + 1, 0, 1);   // prefetch half A

    float sj[4] = {0.f, 0.f, 0.f, 0.f};
    MFMA_DT(0) MFMA_DT(1) MFMA_DT(2) MFMA_DT(3)
    if (tile < 12) LOADK2(tile + 1, 2, 3);   // prefetch half B
    MFMA_DT(4) MFMA_DT(5) MFMA_DT(6) MFMA_DT(7)

    #pragma unroll
    for (int j = 0; j < 4; ++j) sj[j] = sum16(sj[j]);

    unsigned long long mword = tile < 4 ? mw0 : tile < 8 ? mw1 : tile < 12 ? mw2 : mw3;
    float mt = -1e30f;
    #pragma unroll
    for (int j = 0; j < 4; ++j) {
      int bitp = ((tile & 3) << 4) + lrow * 4 + j;
      bool valid = (mword >> bitp) & 1ull;
      sj[j] = valid ? (sj[j] + b2v) : -1e30f;
      mt = fmaxf(mt, sj[j]);
    }
    mt = fmaxf(mt, __shfl_xor(mt, 16));
    mt = fmaxf(mt, __shfl_xor(mt, 32));

    if (mt > m_w) {  // exact defer-max
      float sc = __expf(m_w - mt);
      den_w *= sc;
      #pragma unroll
      for (int i = 0; i < 32; ++i) accpv[i] *= sc;
      m_w = mt;
    }
    float wj[4], dsum = 0.f;
    #pragma unroll
    for (int j = 0; j < 4; ++j) { wj[j] = __expf(sj[j] - m_w); dsum += wj[j]; }
    dsum += __shfl_xor(dsum, 16);
    dsum += __shfl_xor(dsum, 32);
    den_w += dsum;

    // broadcast weight for this lane's K row (t = tile*16 + lcol)
    float tmp = (lcol & 2) ? ((lcol & 1) ? wj[3] : wj[2])
                           : ((lcol & 1) ? wj[1] : wj[0]);
    float wtr = __shfl(tmp, ((lcol >> 2) << 4) | (lcol & 3), 64);

    // PV from bf16 af (unpack + FMA)
    #pragma unroll
    for (int ks = 0; ks < 4; ++ks) {
      #pragma unroll
      for (int i = 0; i < 8; ++i)
        accpv[ks * 8 + i] += wtr * bf2f(af[ks][i]);
    }
  }

  // ---- fold K-rows via DPP; lcol==0 lanes hold 32 f-slots; store directly ----
  #pragma unroll
  for (int i = 0; i < 32; ++i) accpv[i] = sum16(accpv[i]);
  if (lcol == 0) {
    float inv = (den_w > 0.f) ? 1.0f / den_w : 0.f;
    float* ob = outg + (size_t)b * 128;
    #pragma unroll
    for (int ks = 0; ks < 4; ++ks) {
      f32x4 a = {accpv[ks*8+0]*inv, accpv[ks*8+1]*inv, accpv[ks*8+2]*inv, accpv[ks*8+3]*inv};
      f32x4 c = {accpv[ks*8+4]*inv, accpv[ks*8+5]*inv, accpv[ks*8+6]*inv, accpv[ks*8+7]*inv};
      *(f32x4*)(ob + ks * 32 + lrow * 8)     = a;
      *(f32x4*)(ob + ks * 32 + lrow * 8 + 4) = c;
    }
  }
  #undef MFMA_DT
  #undef LOADK2
}

}  // namespace

extern "C" void kernel_launch(void* const* d_in, const int* in_sizes, int n_in,
                              void* d_out, int out_size, void* d_ws, size_t ws_size,
                              hipStream_t stream) {
  (void)in_sizes; (void)n_in; (void)out_size;
  const float* q    = (const float*)d_in[0];
  const float* keys = (const float*)d_in[1];
  const void*  mask = d_in[2];
  const float* w1   = (const float*)d_in[3];
  const float* b1   = (const float*)d_in[4];
  const float* pa   = (const float*)d_in[5];
  const float* w2   = (const float*)d_in[6];
  const float* b2   = (const float*)d_in[7];
  float* out = (float*)d_out;

  unsigned short* Wp = (unsigned short*)d_ws;      // 64 KB bf16 frag table
  float* sTd = (float*)((char*)d_ws + 65536);      // 64 KB (A+C) d-major f32
  int mode = (ws_size >= (size_t)131072) ? 1 : 0;
  if (mode) preW_kernel<<<64, 256, 0, stream>>>(w1, Wp, sTd);
  din_kernel<<<512, 256, 0, stream>>>(q, keys, mask, w1, b1, pa, w2, b2,
                                      Wp, sTd, mode, out);
}